// Round 5
// baseline (230.576 us; speedup 1.0000x reference)
//
#include <hip/hip_runtime.h>
#include <hip/hip_bf16.h>

#define D 128
#define CAT 640
#define BM 32
#define W1F_ELEMS 81920   // 20*8*64*8
#define W2F_ELEMS 16384   // 4*8*64*8
#define NBUCK 4096        // seed>>8 buckets (256-row = 128 KB spans)

typedef __attribute__((ext_vector_type(8))) short bf16x8;
typedef __attribute__((ext_vector_type(4))) short short4v;
typedef __attribute__((ext_vector_type(4))) float f32x4;

static __device__ __forceinline__ unsigned short f32_to_bf16(float f) {
    unsigned u = __float_as_uint(f);
    unsigned r = u + 0x7FFFu + ((u >> 16) & 1u);   // RNE
    return (unsigned short)(r >> 16);
}

// Pack W1 [128][640] and W2 [128][128] (fp32, torch Linear [out,in]) into MFMA
// B-fragment order: (ks, j16, lane, e) = W[j16*16 + (lane&15)][ks*32 + (lane>>4)*8 + e]
__global__ void prep_frags(const float* __restrict__ W1, const float* __restrict__ W2,
                           unsigned short* __restrict__ W1f, unsigned short* __restrict__ W2f) {
    int f = blockIdx.x * 256 + threadIdx.x;
    if (f < W1F_ELEMS) {
        int e = f & 7, l = (f >> 3) & 63, j16 = (f >> 9) & 7, ks = f >> 12;
        int o = j16 * 16 + (l & 15);
        int k = ks * 32 + ((l >> 4) << 3) + e;
        W1f[f] = f32_to_bf16(W1[o * CAT + k]);
    } else if (f < W1F_ELEMS + W2F_ELEMS) {
        int f2 = f - W1F_ELEMS;
        int e = f2 & 7, l = (f2 >> 3) & 63, j16 = (f2 >> 9) & 7, ks = f2 >> 12;
        int o = j16 * 16 + (l & 15);
        int k = ks * 32 + ((l >> 4) << 3) + e;
        W2f[f2] = f32_to_bf16(W2[o * D + k]);
    }
}

// ---- counting sort of seeds by bucket (seed>>8), carrying original index ----
__global__ void zero_counts(int* __restrict__ counts) {
    counts[blockIdx.x * 256 + threadIdx.x] = 0;
}

__global__ void hist_kernel(const int* __restrict__ seeds, int* __restrict__ counts, int B) {
    int i = blockIdx.x * 256 + threadIdx.x;
    if (i < B) atomicAdd(&counts[seeds[i] >> 8], 1);
}

// one block, 1024 threads, each owns 4 buckets: exclusive prefix over NBUCK=4096
__global__ __launch_bounds__(1024) void scan_kernel(const int* __restrict__ counts,
                                                    int* __restrict__ offsets) {
    __shared__ int tsum[1024];
    const int tid = threadIdx.x;
    int c0 = counts[tid * 4 + 0], c1 = counts[tid * 4 + 1];
    int c2 = counts[tid * 4 + 2], c3 = counts[tid * 4 + 3];
    int s = c0 + c1 + c2 + c3;
    tsum[tid] = s;
    __syncthreads();
    for (int off = 1; off < 1024; off <<= 1) {
        int v = 0;
        if (tid >= off) v = tsum[tid - off];
        __syncthreads();
        if (tid >= off) tsum[tid] += v;
        __syncthreads();
    }
    int excl = tsum[tid] - s;
    offsets[tid * 4 + 0] = excl;
    offsets[tid * 4 + 1] = excl + c0;
    offsets[tid * 4 + 2] = excl + c0 + c1;
    offsets[tid * 4 + 3] = excl + c0 + c1 + c2;
}

__global__ void scatter_kernel(const int* __restrict__ seeds, int* __restrict__ offsets,
                               int2* __restrict__ sorted, int B) {
    int i = blockIdx.x * 256 + threadIdx.x;
    if (i < B) {
        int s = seeds[i];
        int pos = atomicAdd(&offsets[s >> 8], 1);
        sorted[pos] = make_int2(s, i);
    }
}

// R1 structure (best measured: bulk decoupled gather -> LDS -> GEMM1 -> GEMM2),
// fed with bucket-sorted (seed, orig) pairs; stores go to orig rows.
// XCD-bijective block swizzle gives each XCD a contiguous sorted range.
__global__ __launch_bounds__(256) void rowmlp_kernel(
    const float* __restrict__ x_rows, const int2* __restrict__ sorted,
    const unsigned short* __restrict__ W1f, const float* __restrict__ b1,
    const unsigned short* __restrict__ W2f, const float* __restrict__ b2,
    float* __restrict__ out, int Nrows, int nwg)
{
    __shared__ __align__(16) unsigned short Ab[BM][CAT];  // 40 KB, XOR-swizzled
    __shared__ __align__(16) unsigned short Hb[BM][D];    // 8 KB, XOR-swizzled
    __shared__ int sseed[BM];
    __shared__ int sorig[BM];

    const int tid = threadIdx.x;
    // bijective XCD swizzle (m204 form)
    int blk;
    {
        int b = blockIdx.x;
        int q = nwg >> 3, r = nwg & 7;
        int xcd = b & 7, k = b >> 3;
        blk = (xcd < r ? xcd * (q + 1) : r * (q + 1) + (xcd - r) * q) + k;
    }

    if (tid < BM) {
        int2 sp = sorted[blk * BM + tid];
        sseed[tid] = sp.x;
        sorig[tid] = sp.y;
    }
    __syncthreads();

    // ---- bulk decoupled gather: 160 segments of 512 B; 8 segments/iter,
    // 20 independent float4 loads per thread, no barriers inside.
    {
        const int lane32 = tid & 31;
        const int segbase = tid >> 5;          // 0..7
        #pragma unroll
        for (int it = 0; it < 20; ++it) {
            int seg = it * 8 + segbase;        // 0..159
            int row = seg / 5;
            int j = seg - row * 5;
            int idx = sseed[row] + j - 2;
            idx = idx < 0 ? 0 : (idx >= Nrows ? Nrows - 1 : idx);
            float4 v = *((const float4*)(x_rows + (size_t)idx * D) + lane32);
            short4v p;
            p[0] = (short)f32_to_bf16(v.x); p[1] = (short)f32_to_bf16(v.y);
            p[2] = (short)f32_to_bf16(v.z); p[3] = (short)f32_to_bf16(v.w);
            int kshort = j * D + lane32 * 4;
            *(short4v*)(&Ab[row][kshort ^ ((row & 7) << 3)]) = p;
        }
    }
    __syncthreads();

    const int wave = tid >> 6;   // 0..3: N-column group
    const int l    = tid & 63;
    const int l15  = l & 15;
    const int lhi  = l >> 4;

    const bf16x8* W1v = (const bf16x8*)W1f;
    const bf16x8* W2v = (const bf16x8*)W2f;

    // ---- GEMM1: h = x_cat @ W1^T  (per wave: M=32, N=32, K=640)
    f32x4 acc[2][2] = {};
    #pragma unroll
    for (int ks = 0; ks < 20; ++ks) {
        bf16x8 a[2], b[2];
        #pragma unroll
        for (int m = 0; m < 2; ++m) {
            int row = m * 16 + l15;
            a[m] = *(const bf16x8*)(&Ab[row][(ks * 32 + lhi * 8) ^ ((row & 7) << 3)]);
        }
        #pragma unroll
        for (int n = 0; n < 2; ++n) {
            int j16 = wave * 2 + n;
            b[n] = W1v[(ks * 8 + j16) * 64 + l];
        }
        #pragma unroll
        for (int m = 0; m < 2; ++m)
            #pragma unroll
            for (int n = 0; n < 2; ++n)
                acc[m][n] = __builtin_amdgcn_mfma_f32_16x16x32_bf16(a[m], b[n], acc[m][n], 0, 0, 0);
    }

    // ---- bias + ReLU -> bf16 h tile (swizzled)
    #pragma unroll
    for (int n = 0; n < 2; ++n) {
        int col = wave * 32 + n * 16 + l15;
        float bias = b1[col];
        #pragma unroll
        for (int m = 0; m < 2; ++m) {
            #pragma unroll
            for (int r = 0; r < 4; ++r) {
                float v = acc[m][n][r] + bias;
                v = v > 0.f ? v : 0.f;
                int row = m * 16 + lhi * 4 + r;   // C/D: col=lane&15, row=(lane>>4)*4+reg
                Hb[row][col ^ ((row & 7) << 3)] = f32_to_bf16(v);
            }
        }
    }
    __syncthreads();

    // ---- GEMM2: out = h @ W2^T  (M=32, N=32 per wave, K=128)
    f32x4 acc2[2][2] = {};
    #pragma unroll
    for (int ks = 0; ks < 4; ++ks) {
        bf16x8 a[2], b[2];
        #pragma unroll
        for (int m = 0; m < 2; ++m) {
            int row = m * 16 + l15;
            a[m] = *(const bf16x8*)(&Hb[row][(ks * 32 + lhi * 8) ^ ((row & 7) << 3)]);
        }
        #pragma unroll
        for (int n = 0; n < 2; ++n) {
            int j16 = wave * 2 + n;
            b[n] = W2v[(ks * 8 + j16) * 64 + l];
        }
        #pragma unroll
        for (int m = 0; m < 2; ++m)
            #pragma unroll
            for (int n = 0; n < 2; ++n)
                acc2[m][n] = __builtin_amdgcn_mfma_f32_16x16x32_bf16(a[m], b[n], acc2[m][n], 0, 0, 0);
    }

    // ---- bias + fp32 store to ORIGINAL rows
    #pragma unroll
    for (int n = 0; n < 2; ++n) {
        int col = wave * 32 + n * 16 + l15;
        float bias = b2[col];
        #pragma unroll
        for (int m = 0; m < 2; ++m) {
            #pragma unroll
            for (int r = 0; r < 4; ++r) {
                int row = m * 16 + lhi * 4 + r;
                out[(size_t)sorig[row] * D + col] = acc2[m][n][r] + bias;
            }
        }
    }
}

extern "C" void kernel_launch(void* const* d_in, const int* in_sizes, int n_in,
                              void* d_out, int out_size, void* d_ws, size_t ws_size,
                              hipStream_t stream) {
    const float* x_rows = (const float*)d_in[0];
    const int*   seeds  = (const int*)d_in[1];
    const float* W1     = (const float*)d_in[2];
    const float* b1     = (const float*)d_in[3];
    const float* W2     = (const float*)d_in[4];
    const float* b2     = (const float*)d_in[5];
    float* out = (float*)d_out;

    int Nrows = in_sizes[0] / D;
    int B = in_sizes[1];

    // d_ws layout
    unsigned short* W1f = (unsigned short*)d_ws;                 // 160 KB
    unsigned short* W2f = W1f + W1F_ELEMS;                       // 32 KB
    int* counts  = (int*)(W2f + W2F_ELEMS);                      // 16 KB
    int* offsets = counts + NBUCK;                               // 16 KB
    int2* sorted = (int2*)(offsets + NBUCK);                     // 8*B bytes

    prep_frags<<<(W1F_ELEMS + W2F_ELEMS + 255) / 256, 256, 0, stream>>>(W1, W2, W1f, W2f);
    zero_counts<<<NBUCK / 256, 256, 0, stream>>>(counts);
    hist_kernel<<<(B + 255) / 256, 256, 0, stream>>>(seeds, counts, B);
    scan_kernel<<<1, 1024, 0, stream>>>(counts, offsets);
    scatter_kernel<<<(B + 255) / 256, 256, 0, stream>>>(seeds, offsets, sorted, B);

    int nwg = B / BM;
    rowmlp_kernel<<<nwg, 256, 0, stream>>>(x_rows, sorted, W1f, b1, W2f, b2, out, Nrows, nwg);
}